// Round 14
// baseline (379.277 us; speedup 1.0000x reference)
//
#include <hip/hip_runtime.h>
#include <math.h>

#define B_ 2
#define S_ 1024
#define D_ 512
#define N_ 4096
#define H_ 8
#define DH_ 64
#define NCAND 288   // 9 neighbor cells * 32 entries
#define TOPK 32
#define NTOK (B_*S_)   // 2048
#define NG2 1152       // max 2-token same-cell groups (8*144)

#define NROWS 16384       // B*H*S
#define NSLOT_BH 8704     // sum over rows i<1024 of (i/64+1)
#define NSLOTS (16*NSLOT_BH)

__device__ __forceinline__ float wave_sum(float v) {
    #pragma unroll
    for (int o = 32; o; o >>= 1) v += __shfl_xor(v, o);
    return v;
}
__device__ __forceinline__ float wave_max(float v) {
    #pragma unroll
    for (int o = 32; o; o >>= 1) v = fmaxf(v, __shfl_xor(v, o));
    return v;
}

// ---------- token sort by spatial cell + 2-token group descriptors ----------
__global__ __launch_bounds__(1024) void sort_tokens_kernel(
    const float* __restrict__ qk_pos, const float* __restrict__ v_pos,
    const float* __restrict__ pos_min, const float* __restrict__ pos_range,
    int* __restrict__ order_qk, int* __restrict__ order_v,
    int2* __restrict__ desc_qk, int2* __restrict__ desc_v)
{
    __shared__ int hist[256], tmp[256], offs[256], startc[256], gcnt[256];
    const int t = threadIdx.x;
    const int pass = blockIdx.x;
    const float pm0 = pos_min[0], pm1 = pos_min[1];
    const float pr0 = pos_range[0], pr1 = pos_range[1];
    const float* pos = pass ? v_pos : qk_pos;
    int* order = pass ? order_v : order_qk;
    int2* desc = pass ? desc_v : desc_qk;
    if (t < NG2) desc[t] = make_int2(0, 0);
    if (t + 1024 < NG2) desc[t + 1024] = make_int2(0, 0);
    if (t < 256) hist[t] = 0;
    __syncthreads();
    int cell[2];
    #pragma unroll
    for (int k = 0; k < 2; k++) {
        int tok = t + k * 1024;
        float p0 = pos[tok * 2], p1 = pos[tok * 2 + 1];
        int cx = min(max((int)((p0 - pm0) / pr0 * 16.f), 0), 15);
        int cy = min(max((int)((p1 - pm1) / pr1 * 16.f), 0), 15);
        cell[k] = cx * 16 + cy;
        atomicAdd(&hist[cell[k]], 1);
    }
    __syncthreads();
    if (t < 256) tmp[t] = hist[t];
    __syncthreads();
    for (int d = 1; d < 256; d <<= 1) {
        int v = 0;
        if (t < 256 && t >= d) v = tmp[t - d];
        __syncthreads();
        if (t < 256) tmp[t] += v;
        __syncthreads();
    }
    if (t < 256) {
        startc[t] = tmp[t] - hist[t];
        offs[t]   = startc[t];
        gcnt[t]   = (hist[t] + 1) >> 1;
    }
    __syncthreads();
    #pragma unroll
    for (int k = 0; k < 2; k++) {
        int tok = t + k * 1024;
        int p = atomicAdd(&offs[cell[k]], 1);
        order[p] = tok;
    }
    __syncthreads();
    if (t < 256) tmp[t] = gcnt[t];
    __syncthreads();
    for (int d = 1; d < 256; d <<= 1) {
        int v = 0;
        if (t < 256 && t >= d) v = tmp[t - d];
        __syncthreads();
        if (t < 256) tmp[t] += v;
        __syncthreads();
    }
    if (t < 256) {
        int g0 = tmp[t] - gcnt[t];
        for (int k = 0; k < gcnt[t]; k++)
            desc[g0 + k] = make_int2(startc[t] + 2 * k, min(2, hist[t] - 2 * k));
    }
}

// ---------- fused QK+V kernel (R13: 16-lane-group dot phase) ----------
__global__ __launch_bounds__(256) void qkv_fused(
    const int2* __restrict__ desc_qk, const int* __restrict__ order_qk,
    const int2* __restrict__ desc_v,  const int* __restrict__ order_v,
    const float* __restrict__ x,
    const float* __restrict__ qk_pos, const float* __restrict__ v_pos,
    const float* __restrict__ tauQ, const float* __restrict__ tauK,
    const float* __restrict__ tauV,
    const float* __restrict__ qk_neurons, const float* __restrict__ v_neurons,
    const float* __restrict__ npos_qk, const float* __restrict__ npos_v,
    const int* __restrict__ cm_qk, const int* __restrict__ cm_v,
    const float* __restrict__ pos_min, const float* __restrict__ pos_range,
    float* __restrict__ Q, float* __restrict__ K, float* __restrict__ V,
    float* __restrict__ posacc)
{
    const int bid = blockIdx.x;
    const int role = bid & 1;
    const int g = bid >> 1;
    const int gid = (g & 7) * 144 + (g >> 3);
    const int2 dsc = role ? desc_v[gid] : desc_qk[gid];
    const int gstart = dsc.x, count = dsc.y;
    if (count == 0) return;

    const int*   order   = role ? order_v   : order_qk;
    const float* pose    = role ? v_pos     : qk_pos;
    const float* neurons = role ? v_neurons : qk_neurons;
    const float* npos    = role ? npos_v    : npos_qk;
    const int*   cmap    = role ? cm_v      : cm_qk;

    __shared__ int   idx[NCAND];
    __shared__ float msk[NCAND];
    __shared__ float act[2][NCAND];
    __shared__ int   ci[2][NCAND];
    __shared__ float cw1[2][NCAND], cw2[2][NCAND];
    __shared__ int   toks[2], cnt2[2];
    __shared__ float red[2][2][4];
    __shared__ float redc;

    const int t = threadIdx.x, wid = t >> 6, lane = t & 63;
    const int sub = lane & 15, grp = lane >> 4;
    if (t < 2) { toks[t] = order[gstart + min(t, count - 1)]; cnt2[t] = 0; }
    __syncthreads();
    const int token0 = toks[0];

    const float pm0 = pos_min[0], pm1 = pos_min[1];
    const float pr0 = pos_range[0], pr1 = pos_range[1];
    {
        const float p0 = pose[token0 * 2], p1 = pose[token0 * 2 + 1];
        const int cx = min(max((int)((p0 - pm0) / pr0 * 16.f), 0), 15);
        const int cy = min(max((int)((p1 - pm1) / pr1 * 16.f), 0), 15);
        for (int c = t; c < NCAND; c += 256) {
            int o = c >> 5, ms = c & 31;
            int nx = min(max(cx + o / 3 - 1, 0), 15), ny = min(max(cy + o % 3 - 1, 0), 15);
            int cand = cmap[(nx * 16 + ny) * 32 + ms];
            idx[c] = cand >= 0 ? cand : 0;
            msk[c] = cand >= 0 ? 1.f : 0.f;
        }
    }
    __syncthreads();

    float4 xr0[8], xr1[8];
    {
        const float4* xp0 = (const float4*)(x + (size_t)toks[0] * D_);
        const float4* xp1 = (const float4*)(x + (size_t)toks[1] * D_);
        #pragma unroll
        for (int k = 0; k < 8; k++) {
            xr0[k] = xp0[k * 16 + sub];
            xr1[k] = xp1[k * 16 + sub];
        }
    }

    const int cb = wid * 72;
    for (int u = 0; u < 72; u += 4) {
        const int c = cb + u + grp;
        const float4* rp = (const float4*)(neurons + (size_t)idx[c] * D_);
        float a0 = 0.f, a1 = 0.f, b0 = 0.f, b1 = 0.f;
        #pragma unroll
        for (int k = 0; k < 8; k += 2) {
            float4 r0 = rp[k * 16 + sub];
            float4 r1 = rp[(k + 1) * 16 + sub];
            a0 += xr0[k].x*r0.x + xr0[k].y*r0.y + xr0[k].z*r0.z + xr0[k].w*r0.w;
            a1 += xr1[k].x*r0.x + xr1[k].y*r0.y + xr1[k].z*r0.z + xr1[k].w*r0.w;
            b0 += xr0[k+1].x*r1.x + xr0[k+1].y*r1.y + xr0[k+1].z*r1.z + xr0[k+1].w*r1.w;
            b1 += xr1[k+1].x*r1.x + xr1[k+1].y*r1.y + xr1[k+1].z*r1.z + xr1[k+1].w*r1.w;
        }
        float f0 = a0 + b0, f1 = a1 + b1;
        #pragma unroll
        for (int o = 1; o <= 8; o <<= 1) {
            f0 += __shfl_xor(f0, o);
            f1 += __shfl_xor(f1, o);
        }
        if (sub == 0) {
            const float mv = msk[c];
            act[0][c] = (mv != 0.f) ? f0 : -1e9f;
            act[1][c] = (mv != 0.f) ? f1 : -1e9f;
        }
    }
    __syncthreads();

    const int tk = wid >> 1, sw = wid & 1, tt = t & 127;
    const int token = toks[tk];
    {
        float ej[5];
        #pragma unroll
        for (int k = 0; k < 5; k++) {
            int j = lane + 64 * k;
            ej[k] = (j < NCAND) ? act[tk][j] : -1e30f;
        }
        for (int e = sw * 144; e < sw * 144 + 144; e++) {
            float ev = act[tk][e];
            int cgt = 0;
            #pragma unroll
            for (int k = 0; k < 5; k++)
                cgt += __popcll(__ballot(ej[k] > ev));
            if (lane == 0 && cgt < TOPK) {
                int p = atomicAdd(&cnt2[tk], 1);
                ci[tk][p] = e;
            }
        }
    }
    if (wid == 0) {
        float cmv = 0.f;
        for (int c = lane; c < NCAND; c += 64) cmv += msk[c];
        cmv = wave_sum(cmv);
        if (lane == 0) redc = cmv;
    }
    __syncthreads();
    const float cm = redc;
    const int n = cnt2[tk];

    if (role == 0) {
        const float tq = tauQ[token], tkk = tauK[token];
        float sQ = 0.f, sK = 0.f, mQ = 0.f, mK = 0.f;
        for (int p = tt; p < n; p += 128) {
            float s = act[tk][ci[tk][p]];
            float rq = s - tq;
            float gq = (rq > 0.f) ? rq : 1e-8f * __expf(rq);
            float egq = __expf(gq) - 1.f;
            float rk = s - tkk;
            float gk = (rk > 0.f) ? rk : 1e-8f * __expf(rk);
            float egk = __expf(gk) - 1.f;
            cw1[tk][p] = egq; cw2[tk][p] = egk;
            sQ += egq; sK += egk;
            mQ = fmaxf(mQ, egq); mK = fmaxf(mK, egk);
        }
        sQ = wave_sum(sQ); mQ = wave_max(mQ);
        sK = wave_sum(sK); mK = wave_max(mK);
        if (lane == 0) {
            red[tk][sw][0] = sQ; red[tk][sw][1] = mQ;
            red[tk][sw][2] = sK; red[tk][sw][3] = mK;
        }
        __syncthreads();
        const float scQ = tanhf(fmaxf(red[tk][0][1], red[tk][1][1]))
                        / (red[tk][0][0] + red[tk][1][0] + 1e-8f);
        const float scK = tanhf(fmaxf(red[tk][0][3], red[tk][1][3]))
                        / (red[tk][0][2] + red[tk][1][2] + 1e-8f);
        __syncthreads();

        const float qp0 = pose[token * 2], qp1 = pose[token * 2 + 1];
        float plq = 0.f;
        for (int p = tt; p < n; p += 128) {
            int e = ci[tk][p];
            int id = idx[e];
            float m = msk[e], a = act[tk][e];
            float gq = cw1[tk][p] * scQ;
            cw1[tk][p] = a * gq * m;
            cw2[tk][p] = a * cw2[tk][p] * scK * m;
            ci[tk][p] = id;
            float d0 = qp0 - npos[id * 2], d1 = qp1 - npos[id * 2 + 1];
            plq += gq * (d0 * d0 + d1 * d1) * m;
        }
        plq = wave_sum(plq);
        if (lane == 0) red[tk][sw][0] = plq;
        __syncthreads();
        if (tt == 0 && tk < count) {
            int chunk = (token & 1023) >> 7;
            atomicAdd(&posacc[chunk], red[tk][0][0] + red[tk][1][0]);
            atomicAdd(&posacc[8 + chunk], cm);
        }

        if (tk < count) {
            float4 qa = {0,0,0,0}, ka = {0,0,0,0};
            int p = 0;
            for (; p + 1 < n; p += 2) {
                const float4 rA = *(const float4*)(neurons + (size_t)ci[tk][p] * D_ + tt * 4);
                const float4 rB = *(const float4*)(neurons + (size_t)ci[tk][p + 1] * D_ + tt * 4);
                const float wA = cw1[tk][p], bA = cw2[tk][p];
                const float wB = cw1[tk][p + 1], bB = cw2[tk][p + 1];
                qa.x += wA * rA.x + wB * rB.x; qa.y += wA * rA.y + wB * rB.y;
                qa.z += wA * rA.z + wB * rB.z; qa.w += wA * rA.w + wB * rB.w;
                ka.x += bA * rA.x + bB * rB.x; ka.y += bA * rA.y + bB * rB.y;
                ka.z += bA * rA.z + bB * rB.z; ka.w += bA * rA.w + bB * rB.w;
            }
            if (p < n) {
                const float4 rA = *(const float4*)(neurons + (size_t)ci[tk][p] * D_ + tt * 4);
                const float wA = cw1[tk][p], bA = cw2[tk][p];
                qa.x += wA * rA.x; qa.y += wA * rA.y; qa.z += wA * rA.z; qa.w += wA * rA.w;
                ka.x += bA * rA.x; ka.y += bA * rA.y; ka.z += bA * rA.z; ka.w += bA * rA.w;
            }
            *(float4*)(Q + (size_t)token * D_ + tt * 4) = qa;
            *(float4*)(K + (size_t)token * D_ + tt * 4) = ka;
        }
    } else {
        const float tv = tauV[token];
        float sV = 0.f, mV = 0.f;
        for (int p = tt; p < n; p += 128) {
            float s = act[tk][ci[tk][p]];
            float rv = s - tv;
            float gv = (rv > 0.f) ? rv : 1e-8f * __expf(rv);
            float egv = __expf(gv) - 1.f;
            cw1[tk][p] = egv;
            sV += egv; mV = fmaxf(mV, egv);
        }
        sV = wave_sum(sV); mV = wave_max(mV);
        if (lane == 0) { red[tk][sw][0] = sV; red[tk][sw][1] = mV; }
        __syncthreads();
        const float scV = tanhf(fmaxf(red[tk][0][1], red[tk][1][1]))
                        / (red[tk][0][0] + red[tk][1][0] + 1e-8f);
        __syncthreads();

        const float vp0 = pose[token * 2], vp1 = pose[token * 2 + 1];
        float plv = 0.f;
        for (int p = tt; p < n; p += 128) {
            int e = ci[tk][p];
            int id = idx[e];
            float m = msk[e], a = act[tk][e];
            float gv = cw1[tk][p] * scV;
            cw1[tk][p] = a * gv * m;
            ci[tk][p] = id;
            float d0 = vp0 - npos[id * 2], d1 = vp1 - npos[id * 2 + 1];
            plv += gv * (d0 * d0 + d1 * d1) * m;
        }
        plv = wave_sum(plv);
        if (lane == 0) red[tk][sw][0] = plv;
        __syncthreads();
        if (tt == 0 && tk < count) {
            int chunk = (token & 1023) >> 7;
            atomicAdd(&posacc[16 + chunk], red[tk][0][0] + red[tk][1][0]);
            atomicAdd(&posacc[24 + chunk], cm);
        }

        if (tk < count) {
            float4 va = {0,0,0,0};
            int p = 0;
            for (; p + 1 < n; p += 2) {
                const float4 rA = *(const float4*)(neurons + (size_t)ci[tk][p] * D_ + tt * 4);
                const float4 rB = *(const float4*)(neurons + (size_t)ci[tk][p + 1] * D_ + tt * 4);
                const float wA = cw1[tk][p], wB = cw1[tk][p + 1];
                va.x += wA * rA.x + wB * rB.x; va.y += wA * rA.y + wB * rB.y;
                va.z += wA * rA.z + wB * rB.z; va.w += wA * rA.w + wB * rB.w;
            }
            if (p < n) {
                const float4 rA = *(const float4*)(neurons + (size_t)ci[tk][p] * D_ + tt * 4);
                const float wA = cw1[tk][p];
                va.x += wA * rA.x; va.y += wA * rA.y; va.z += wA * rA.z; va.w += wA * rA.w;
            }
            *(float4*)(V + (size_t)token * D_ + tt * 4) = va;
        }
    }
}

// ---------- attention partials (unchanged) ----------
__global__ __launch_bounds__(128) void attn_partial_kernel(
    const float* __restrict__ Q, const float* __restrict__ K,
    const float* __restrict__ V,
    float* __restrict__ pm, float* __restrict__ pl, float* __restrict__ po)
{
    const int xx = blockIdx.x & 7;
    int k = blockIdx.x >> 3;             // 0..143
    const int bh = xx + 8 * (k >= 72);
    k = (k >= 72) ? k - 72 : k;          // 0..71
    int rblk = 0;
    while (k >= 2 * (rblk + 1)) { k -= 2 * (rblk + 1); rblk++; }
    const int sp = k;
    const int b = bh >> 3, h = bh & 7;
    const int j0 = sp * 64;
    const int rbase = rblk * 128;

    const int t = threadIdx.x;
    const int p = t >> 1, dhalf = t & 1;
    const int r0 = rbase + p, r1 = r0 + 64;

    __shared__ float Kl[64 * 64];
    __shared__ float Vl[64 * 64];

    {
        const float* Kbase = K + (size_t)b * S_ * D_ + h * DH_;
        const float* Vbase = V + (size_t)b * S_ * D_ + h * DH_;
        const int lrow = t >> 4, lcol = (t & 15) * 4;
        #pragma unroll
        for (int kk = 0; kk < 8; kk++) {
            const int row = lrow + kk * 8;
            const size_t goff = (size_t)(j0 + row) * D_ + lcol;
            *(float4*)(&Kl[row * 64 + lcol]) = *(const float4*)(Kbase + goff);
            *(float4*)(&Vl[row * 64 + lcol]) = *(const float4*)(Vbase + goff);
        }
    }

    float q0[32], q1[32];
    {
        const float* Qb = Q + (size_t)b * S_ * D_ + h * DH_ + dhalf * 32;
        const float4* qa = (const float4*)(Qb + (size_t)r0 * D_);
        const float4* qb = (const float4*)(Qb + (size_t)r1 * D_);
        #pragma unroll
        for (int kk = 0; kk < 8; kk++) {
            float4 v = qa[kk];
            q0[4*kk] = v.x; q0[4*kk+1] = v.y; q0[4*kk+2] = v.z; q0[4*kk+3] = v.w;
            float4 u = qb[kk];
            q1[4*kk] = u.x; q1[4*kk+1] = u.y; q1[4*kk+2] = u.z; q1[4*kk+3] = u.w;
        }
    }
    float o0[32], o1[32];
    #pragma unroll
    for (int d = 0; d < 32; d++) { o0[d] = 0.f; o1[d] = 0.f; }
    float m0 = -INFINITY, m1 = -INFINITY, l0 = 0.f, l1 = 0.f;

    __syncthreads();

    for (int bb = 0; bb < 8; bb++) {
        const int jb = bb * 8;
        float s0[8], s1[8];
        #pragma unroll
        for (int jj = 0; jj < 8; jj++) {
            const float* kr = &Kl[(jb + jj) * 64 + dhalf * 32];
            float pa0 = 0.f, pb0 = 0.f, pa1 = 0.f, pb1 = 0.f;
            #pragma unroll
            for (int d = 0; d < 32; d += 8) {
                float4 ka = *(const float4*)(kr + d);
                float4 kb = *(const float4*)(kr + d + 4);
                pa0 += q0[d]*ka.x + q0[d+1]*ka.y + q0[d+2]*ka.z + q0[d+3]*ka.w;
                pb0 += q0[d+4]*kb.x + q0[d+5]*kb.y + q0[d+6]*kb.z + q0[d+7]*kb.w;
                pa1 += q1[d]*ka.x + q1[d+1]*ka.y + q1[d+2]*ka.z + q1[d+3]*ka.w;
                pb1 += q1[d+4]*kb.x + q1[d+5]*kb.y + q1[d+6]*kb.z + q1[d+7]*kb.w;
            }
            float f0 = pa0 + pb0, f1 = pa1 + pb1;
            f0 += __shfl_xor(f0, 1);
            f1 += __shfl_xor(f1, 1);
            const int jg = j0 + jb + jj;
            s0[jj] = (jg <= r0) ? f0 * 0.125f : -INFINITY;
            s1[jj] = (jg <= r1) ? f1 * 0.125f : -INFINITY;
        }
        float t0 = s0[0], t1 = s1[0];
        #pragma unroll
        for (int jj = 1; jj < 8; jj++) { t0 = fmaxf(t0, s0[jj]); t1 = fmaxf(t1, s1[jj]); }
        const float nm0 = fmaxf(m0, t0), nm1 = fmaxf(m1, t1);
        const float base0 = (nm0 == -INFINITY) ? 0.f : nm0;
        const float base1 = (nm1 == -INFINITY) ? 0.f : nm1;
        const float al0 = __expf(m0 - base0);
        const float al1 = __expf(m1 - base1);
        float ps0 = 0.f, ps1 = 0.f;
        #pragma unroll
        for (int jj = 0; jj < 8; jj++) {
            s0[jj] = __expf(s0[jj] - base0); ps0 += s0[jj];
            s1[jj] = __expf(s1[jj] - base1); ps1 += s1[jj];
        }
        l0 = l0 * al0 + ps0; l1 = l1 * al1 + ps1;
        #pragma unroll
        for (int d = 0; d < 32; d++) { o0[d] *= al0; o1[d] *= al1; }
        #pragma unroll
        for (int jj = 0; jj < 8; jj++) {
            const float* vr = &Vl[(jb + jj) * 64 + dhalf * 32];
            const float w0 = s0[jj], w1 = s1[jj];
            #pragma unroll
            for (int d = 0; d < 32; d += 4) {
                float4 vv = *(const float4*)(vr + d);
                o0[d]   += w0 * vv.x; o0[d+1] += w0 * vv.y;
                o0[d+2] += w0 * vv.z; o0[d+3] += w0 * vv.w;
                o1[d]   += w1 * vv.x; o1[d+1] += w1 * vv.y;
                o1[d+2] += w1 * vv.z; o1[d+3] += w1 * vv.w;
            }
        }
        m0 = nm0; m1 = nm1;
    }

    if (j0 <= r0) {
        const int g = r0 >> 6;
        const size_t slot = (size_t)bh * NSLOT_BH + 32 * g * (g + 1)
                          + (size_t)(r0 & 63) * (g + 1) + sp;
        if (dhalf == 0) { pm[slot] = m0; pl[slot] = l0; }
        float* od = po + slot * 64 + dhalf * 32;
        #pragma unroll
        for (int kk = 0; kk < 8; kk++) {
            float4 v; v.x = o0[4*kk]; v.y = o0[4*kk+1]; v.z = o0[4*kk+2]; v.w = o0[4*kk+3];
            *(float4*)(od + 4*kk) = v;
        }
    }
    {
        const int g = r1 >> 6;
        const size_t slot = (size_t)bh * NSLOT_BH + 32 * g * (g + 1)
                          + (size_t)(r1 & 63) * (g + 1) + sp;
        if (dhalf == 0) { pm[slot] = m1; pl[slot] = l1; }
        float* od = po + slot * 64 + dhalf * 32;
        #pragma unroll
        for (int kk = 0; kk < 8; kk++) {
            float4 v; v.x = o1[4*kk]; v.y = o1[4*kk+1]; v.z = o1[4*kk+2]; v.w = o1[4*kk+3];
            *(float4*)(od + 4*kk) = v;
        }
    }
}

// ---------- merge split partials (single-pass online merge) ----------
__global__ __launch_bounds__(256) void attn_combine_kernel(
    const float* __restrict__ pm, const float* __restrict__ pl,
    const float* __restrict__ po, float* __restrict__ AO)
{
    const int gth = blockIdx.x * 256 + threadIdx.x;
    const int r = gth >> 6, d = gth & 63;
    const int i = r & 1023, bh = r >> 10;
    const int b = bh >> 3, h = bh & 7;
    const int g = i >> 6;
    const int ns = g + 1;
    const size_t slot0 = (size_t)bh * NSLOT_BH + 32 * g * (g + 1)
                       + (size_t)(i & 63) * (g + 1);
    float mstar = -INFINITY, lstar = 0.f, ostar = 0.f;
    for (int s = 0; s < ns; s++) {
        const float mi = pm[slot0 + s];
        const float nm = fmaxf(mstar, mi);
        const float a = __expf(mstar - nm);      // first iter: exp(-inf)=0
        const float w = __expf(mi - nm);
        lstar = lstar * a + pl[slot0 + s] * w;
        ostar = ostar * a + po[(slot0 + s) * 64 + d] * w;
        mstar = nm;
    }
    AO[((size_t)(b * S_ + i)) * D_ + h * DH_ + d] = ostar / lstar;
}

// ---------- zero out (out re-poisoned each launch; proj uses atomics) ----------
__global__ void zero_out_kernel(float4* __restrict__ o) {
    o[(size_t)blockIdx.x * 256 + threadIdx.x] = make_float4(0.f, 0.f, 0.f, 0.f);
}

// ---------- projection: split-K x2, 4 tokens per block, atomic accumulate ----
__global__ __launch_bounds__(256) void proj_kernel(
    const float* __restrict__ A, const float* __restrict__ W,
    float* __restrict__ out)
{
    __shared__ float rows[4][256];
    const int blk = blockIdx.x;            // 1024 blocks = 512 tokgrp x 2 halves
    const int tg = blk >> 1, half = blk & 1;
    const int d0 = half * 256;
    const int t = threadIdx.x;
    {
        const int j = t >> 6, c = t & 63;  // 4 tokens x 64 float4 chunks
        const float4* af = (const float4*)(A + (size_t)(tg * 4 + j) * D_ + d0);
        ((float4*)&rows[j][0])[c] = af[c];
    }
    __syncthreads();
    float acc0[4] = {0,0,0,0}, acc1[4] = {0,0,0,0};
    for (int d = 0; d < 256; d += 4) {
        float r0[4], r1[4], r2[4], r3[4];
        *(float4*)r0 = *(const float4*)&rows[0][d];
        *(float4*)r1 = *(const float4*)&rows[1][d];
        *(float4*)r2 = *(const float4*)&rows[2][d];
        *(float4*)r3 = *(const float4*)&rows[3][d];
        #pragma unroll
        for (int j = 0; j < 4; j++) {
            float w0 = W[(size_t)(d0 + d + j) * D_ + t];
            float w1 = W[(size_t)(d0 + d + j) * D_ + t + 256];
            acc0[0] += r0[j] * w0; acc1[0] += r0[j] * w1;
            acc0[1] += r1[j] * w0; acc1[1] += r1[j] * w1;
            acc0[2] += r2[j] * w0; acc1[2] += r2[j] * w1;
            acc0[3] += r3[j] * w0; acc1[3] += r3[j] * w1;
        }
    }
    #pragma unroll
    for (int k = 0; k < 4; k++) {
        const size_t base = (size_t)(tg * 4 + k) * D_;
        atomicAdd(&out[base + t], acc0[k]);
        atomicAdd(&out[base + t + 256], acc1[k]);
    }
}

// ---------- pos-loss helpers ----------
__global__ void zero_acc_kernel(float* acc) {
    if (threadIdx.x < 32) acc[threadIdx.x] = 0.f;
}
__global__ void ploss_kernel(const float* __restrict__ acc, float* __restrict__ out) {
    float ssum = 0.f;
    for (int c = 0; c < 8; c++) {
        ssum += acc[c]      / (acc[8 + c]  + 1e-8f);
        ssum += acc[16 + c] / (acc[24 + c] + 1e-8f);
    }
    out[0] = ssum * 0.125f;
}

extern "C" void kernel_launch(void* const* d_in, const int* in_sizes, int n_in,
                              void* d_out, int out_size, void* d_ws, size_t ws_size,
                              hipStream_t stream) {
    const float* x          = (const float*)d_in[0];
    const float* qk_pos     = (const float*)d_in[1];
    const float* v_pos      = (const float*)d_in[2];
    const float* tauQ       = (const float*)d_in[3];
    const float* tauK       = (const float*)d_in[4];
    const float* tauV       = (const float*)d_in[5];
    const float* qk_neurons = (const float*)d_in[6];
    const float* v_neurons  = (const float*)d_in[7];
    const float* npos_qk    = (const float*)d_in[8];
    const float* npos_v     = (const float*)d_in[9];
    const int*   cm_qk      = (const int*)d_in[10];
    const int*   cm_v       = (const int*)d_in[11];
    const float* pos_min    = (const float*)d_in[12];
    const float* pos_range  = (const float*)d_in[13];
    const float* expand_O   = (const float*)d_in[14];

    float* ws = (float*)d_ws;
    const size_t TDf = (size_t)NTOK * D_;     // 1,048,576 floats
    float* Q   = ws;
    float* K   = ws + TDf;
    float* V   = ws + 2 * TDf;
    float* AO  = ws + 3 * TDf;
    float* acc = ws + 4 * TDf;                // 64 float slots
    int*   order_qk = (int*)(ws + 4 * TDf + 64);
    int*   order_v  = order_qk + NTOK;
    int2*  desc_qk  = (int2*)(order_v + NTOK);
    int2*  desc_v   = desc_qk + NG2;
    const size_t head = 4 * TDf + 64 + 2 * NTOK + 4 * NG2;  // float units

    float* pm = ws + head;                    // NSLOTS
    float* pl = pm + (size_t)NSLOTS;
    float* po = pl + (size_t)NSLOTS;          // NSLOTS*64

    float* out = (float*)d_out;

    zero_acc_kernel<<<1, 64, 0, stream>>>(acc);
    zero_out_kernel<<<TDf / 1024, 256, 0, stream>>>((float4*)out);
    sort_tokens_kernel<<<2, 1024, 0, stream>>>(qk_pos, v_pos, pos_min, pos_range,
                                               order_qk, order_v, desc_qk, desc_v);
    qkv_fused<<<2 * NG2, 256, 0, stream>>>(desc_qk, order_qk, desc_v, order_v,
                                           x, qk_pos, v_pos, tauQ, tauK, tauV,
                                           qk_neurons, v_neurons, npos_qk, npos_v,
                                           cm_qk, cm_v, pos_min, pos_range,
                                           Q, K, V, acc);
    attn_partial_kernel<<<1152, 128, 0, stream>>>(Q, K, V, pm, pl, po);
    attn_combine_kernel<<<(NROWS * 64) / 256, 256, 0, stream>>>(pm, pl, po, AO);
    proj_kernel<<<NTOK / 2, 256, 0, stream>>>(AO, expand_O, out);
    ploss_kernel<<<1, 1, 0, stream>>>(acc, out + TDf);
}

// Round 15
// 337.712 us; speedup vs baseline: 1.1231x; 1.1231x over previous
//
#include <hip/hip_runtime.h>
#include <math.h>

#define B_ 2
#define S_ 1024
#define D_ 512
#define N_ 4096
#define H_ 8
#define DH_ 64
#define NCAND 288   // 9 neighbor cells * 32 entries
#define TOPK 32
#define NTOK (B_*S_)   // 2048
#define NG2 1152       // max 2-token same-cell groups (8*144)

#define NROWS 16384       // B*H*S
#define NSLOT_BH 8704     // sum over rows i<1024 of (i/64+1)
#define NSLOTS (16*NSLOT_BH)

__device__ __forceinline__ float wave_sum(float v) {
    #pragma unroll
    for (int o = 32; o; o >>= 1) v += __shfl_xor(v, o);
    return v;
}
__device__ __forceinline__ float wave_max(float v) {
    #pragma unroll
    for (int o = 32; o; o >>= 1) v = fmaxf(v, __shfl_xor(v, o));
    return v;
}

// ---------- token sort by spatial cell + 2-token group descriptors ----------
__global__ __launch_bounds__(1024) void sort_tokens_kernel(
    const float* __restrict__ qk_pos, const float* __restrict__ v_pos,
    const float* __restrict__ pos_min, const float* __restrict__ pos_range,
    int* __restrict__ order_qk, int* __restrict__ order_v,
    int2* __restrict__ desc_qk, int2* __restrict__ desc_v)
{
    __shared__ int hist[256], tmp[256], offs[256], startc[256], gcnt[256];
    const int t = threadIdx.x;
    const int pass = blockIdx.x;
    const float pm0 = pos_min[0], pm1 = pos_min[1];
    const float pr0 = pos_range[0], pr1 = pos_range[1];
    const float* pos = pass ? v_pos : qk_pos;
    int* order = pass ? order_v : order_qk;
    int2* desc = pass ? desc_v : desc_qk;
    if (t < NG2) desc[t] = make_int2(0, 0);
    if (t + 1024 < NG2) desc[t + 1024] = make_int2(0, 0);
    if (t < 256) hist[t] = 0;
    __syncthreads();
    int cell[2];
    #pragma unroll
    for (int k = 0; k < 2; k++) {
        int tok = t + k * 1024;
        float p0 = pos[tok * 2], p1 = pos[tok * 2 + 1];
        int cx = min(max((int)((p0 - pm0) / pr0 * 16.f), 0), 15);
        int cy = min(max((int)((p1 - pm1) / pr1 * 16.f), 0), 15);
        cell[k] = cx * 16 + cy;
        atomicAdd(&hist[cell[k]], 1);
    }
    __syncthreads();
    if (t < 256) tmp[t] = hist[t];
    __syncthreads();
    for (int d = 1; d < 256; d <<= 1) {
        int v = 0;
        if (t < 256 && t >= d) v = tmp[t - d];
        __syncthreads();
        if (t < 256) tmp[t] += v;
        __syncthreads();
    }
    if (t < 256) {
        startc[t] = tmp[t] - hist[t];
        offs[t]   = startc[t];
        gcnt[t]   = (hist[t] + 1) >> 1;
    }
    __syncthreads();
    #pragma unroll
    for (int k = 0; k < 2; k++) {
        int tok = t + k * 1024;
        int p = atomicAdd(&offs[cell[k]], 1);
        order[p] = tok;
    }
    __syncthreads();
    if (t < 256) tmp[t] = gcnt[t];
    __syncthreads();
    for (int d = 1; d < 256; d <<= 1) {
        int v = 0;
        if (t < 256 && t >= d) v = tmp[t - d];
        __syncthreads();
        if (t < 256) tmp[t] += v;
        __syncthreads();
    }
    if (t < 256) {
        int g0 = tmp[t] - gcnt[t];
        for (int k = 0; k < gcnt[t]; k++)
            desc[g0 + k] = make_int2(startc[t] + 2 * k, min(2, hist[t] - 2 * k));
    }
}

// ---------- fused QK+V kernel (R13 dot; rank = 32-step binary search) -------
__global__ __launch_bounds__(256) void qkv_fused(
    const int2* __restrict__ desc_qk, const int* __restrict__ order_qk,
    const int2* __restrict__ desc_v,  const int* __restrict__ order_v,
    const float* __restrict__ x,
    const float* __restrict__ qk_pos, const float* __restrict__ v_pos,
    const float* __restrict__ tauQ, const float* __restrict__ tauK,
    const float* __restrict__ tauV,
    const float* __restrict__ qk_neurons, const float* __restrict__ v_neurons,
    const float* __restrict__ npos_qk, const float* __restrict__ npos_v,
    const int* __restrict__ cm_qk, const int* __restrict__ cm_v,
    const float* __restrict__ pos_min, const float* __restrict__ pos_range,
    float* __restrict__ Q, float* __restrict__ K, float* __restrict__ V,
    float* __restrict__ posacc)
{
    const int bid = blockIdx.x;
    const int role = bid & 1;
    const int g = bid >> 1;
    const int gid = (g & 7) * 144 + (g >> 3);
    const int2 dsc = role ? desc_v[gid] : desc_qk[gid];
    const int gstart = dsc.x, count = dsc.y;
    if (count == 0) return;

    const int*   order   = role ? order_v   : order_qk;
    const float* pose    = role ? v_pos     : qk_pos;
    const float* neurons = role ? v_neurons : qk_neurons;
    const float* npos    = role ? npos_v    : npos_qk;
    const int*   cmap    = role ? cm_v      : cm_qk;

    __shared__ int   idx[NCAND];
    __shared__ float msk[NCAND];
    __shared__ float act[2][NCAND];
    __shared__ int   ci[2][NCAND];
    __shared__ float cw1[2][NCAND], cw2[2][NCAND];
    __shared__ int   toks[2], cnt2[2];
    __shared__ float red[2][2][4];
    __shared__ float redc;

    const int t = threadIdx.x, wid = t >> 6, lane = t & 63;
    const int sub = lane & 15, grp = lane >> 4;
    if (t < 2) { toks[t] = order[gstart + min(t, count - 1)]; cnt2[t] = 0; }
    __syncthreads();
    const int token0 = toks[0];

    const float pm0 = pos_min[0], pm1 = pos_min[1];
    const float pr0 = pos_range[0], pr1 = pos_range[1];
    {
        const float p0 = pose[token0 * 2], p1 = pose[token0 * 2 + 1];
        const int cx = min(max((int)((p0 - pm0) / pr0 * 16.f), 0), 15);
        const int cy = min(max((int)((p1 - pm1) / pr1 * 16.f), 0), 15);
        for (int c = t; c < NCAND; c += 256) {
            int o = c >> 5, ms = c & 31;
            int nx = min(max(cx + o / 3 - 1, 0), 15), ny = min(max(cy + o % 3 - 1, 0), 15);
            int cand = cmap[(nx * 16 + ny) * 32 + ms];
            idx[c] = cand >= 0 ? cand : 0;
            msk[c] = cand >= 0 ? 1.f : 0.f;
        }
    }
    __syncthreads();

    float4 xr0[8], xr1[8];
    {
        const float4* xp0 = (const float4*)(x + (size_t)toks[0] * D_);
        const float4* xp1 = (const float4*)(x + (size_t)toks[1] * D_);
        #pragma unroll
        for (int k = 0; k < 8; k++) {
            xr0[k] = xp0[k * 16 + sub];
            xr1[k] = xp1[k * 16 + sub];
        }
    }

    // --- dot phase: 16-lane groups, 4 candidates per wave-iteration ---
    const int cb = wid * 72;
    for (int u = 0; u < 72; u += 4) {
        const int c = cb + u + grp;
        const float4* rp = (const float4*)(neurons + (size_t)idx[c] * D_);
        float a0 = 0.f, a1 = 0.f, b0 = 0.f, b1 = 0.f;
        #pragma unroll
        for (int k = 0; k < 8; k += 2) {
            float4 r0 = rp[k * 16 + sub];
            float4 r1 = rp[(k + 1) * 16 + sub];
            a0 += xr0[k].x*r0.x + xr0[k].y*r0.y + xr0[k].z*r0.z + xr0[k].w*r0.w;
            a1 += xr1[k].x*r0.x + xr1[k].y*r0.y + xr1[k].z*r0.z + xr1[k].w*r0.w;
            b0 += xr0[k+1].x*r1.x + xr0[k+1].y*r1.y + xr0[k+1].z*r1.z + xr0[k+1].w*r1.w;
            b1 += xr1[k+1].x*r1.x + xr1[k+1].y*r1.y + xr1[k+1].z*r1.z + xr1[k+1].w*r1.w;
        }
        float f0 = a0 + b0, f1 = a1 + b1;
        #pragma unroll
        for (int o = 1; o <= 8; o <<= 1) {
            f0 += __shfl_xor(f0, o);
            f1 += __shfl_xor(f1, o);
        }
        if (sub == 0) {
            const float mv = msk[c];
            act[0][c] = (mv != 0.f) ? f0 : -1e9f;
            act[1][c] = (mv != 0.f) ? f1 : -1e9f;
        }
    }
    __syncthreads();

    const int tk = wid >> 1, sw = wid & 1, tt = t & 127;
    const int token = toks[tk];

    // --- rank: wave sw==0 of each pair; exact Kth-largest via bitwise search.
    // keep iff #strictly-greater < K  <=>  v >= v_(K) (ties all kept).
    if (sw == 0) {
        unsigned ej[5];
        #pragma unroll
        for (int k = 0; k < 5; k++) {
            int j = lane + 64 * k;
            float f = (j < NCAND) ? act[tk][j] : -1e30f;   // pad: never kept
            unsigned uu = __float_as_uint(f);
            ej[k] = (uu & 0x80000000u) ? ~uu : (uu | 0x80000000u);
        }
        unsigned T = 0u;
        for (int bit = 31; bit >= 0; bit--) {
            const unsigned cand = T | (1u << bit);
            int c = 0;
            #pragma unroll
            for (int k = 0; k < 5; k++)
                c += __popcll(__ballot(ej[k] >= cand));
            if (c >= TOPK) T = cand;
        }
        // deterministic compaction in index order (no atomics)
        int base = 0;
        const unsigned long long below = (lane == 0) ? 0ull
                                       : (~0ull >> (64 - lane));
        #pragma unroll
        for (int k = 0; k < 5; k++) {
            const unsigned long long mk2 = __ballot(ej[k] >= T);
            if (ej[k] >= T) {
                int pos = base + __popcll(mk2 & below);
                ci[tk][pos] = lane + 64 * k;
            }
            base += __popcll(mk2);
        }
        if (lane == 0) cnt2[tk] = base;
    }
    if (wid == 0) {
        float cmv = 0.f;
        for (int c = lane; c < NCAND; c += 64) cmv += msk[c];
        cmv = wave_sum(cmv);
        if (lane == 0) redc = cmv;
    }
    __syncthreads();
    const float cm = redc;
    const int n = cnt2[tk];

    if (role == 0) {
        const float tq = tauQ[token], tkk = tauK[token];
        float sQ = 0.f, sK = 0.f, mQ = 0.f, mK = 0.f;
        for (int p = tt; p < n; p += 128) {
            float s = act[tk][ci[tk][p]];
            float rq = s - tq;
            float gq = (rq > 0.f) ? rq : 1e-8f * __expf(rq);
            float egq = __expf(gq) - 1.f;
            float rk = s - tkk;
            float gk = (rk > 0.f) ? rk : 1e-8f * __expf(rk);
            float egk = __expf(gk) - 1.f;
            cw1[tk][p] = egq; cw2[tk][p] = egk;
            sQ += egq; sK += egk;
            mQ = fmaxf(mQ, egq); mK = fmaxf(mK, egk);
        }
        sQ = wave_sum(sQ); mQ = wave_max(mQ);
        sK = wave_sum(sK); mK = wave_max(mK);
        if (lane == 0) {
            red[tk][sw][0] = sQ; red[tk][sw][1] = mQ;
            red[tk][sw][2] = sK; red[tk][sw][3] = mK;
        }
        __syncthreads();
        const float scQ = tanhf(fmaxf(red[tk][0][1], red[tk][1][1]))
                        / (red[tk][0][0] + red[tk][1][0] + 1e-8f);
        const float scK = tanhf(fmaxf(red[tk][0][3], red[tk][1][3]))
                        / (red[tk][0][2] + red[tk][1][2] + 1e-8f);
        __syncthreads();

        const float qp0 = pose[token * 2], qp1 = pose[token * 2 + 1];
        float plq = 0.f;
        for (int p = tt; p < n; p += 128) {
            int e = ci[tk][p];
            int id = idx[e];
            float m = msk[e], a = act[tk][e];
            float gq = cw1[tk][p] * scQ;
            cw1[tk][p] = a * gq * m;
            cw2[tk][p] = a * cw2[tk][p] * scK * m;
            ci[tk][p] = id;
            float d0 = qp0 - npos[id * 2], d1 = qp1 - npos[id * 2 + 1];
            plq += gq * (d0 * d0 + d1 * d1) * m;
        }
        plq = wave_sum(plq);
        if (lane == 0) red[tk][sw][0] = plq;
        __syncthreads();
        if (tt == 0 && tk < count) {
            int chunk = (token & 1023) >> 7;
            atomicAdd(&posacc[chunk], red[tk][0][0] + red[tk][1][0]);
            atomicAdd(&posacc[8 + chunk], cm);
        }

        if (tk < count) {
            float4 qa = {0,0,0,0}, ka = {0,0,0,0};
            int p = 0;
            for (; p + 1 < n; p += 2) {
                const float4 rA = *(const float4*)(neurons + (size_t)ci[tk][p] * D_ + tt * 4);
                const float4 rB = *(const float4*)(neurons + (size_t)ci[tk][p + 1] * D_ + tt * 4);
                const float wA = cw1[tk][p], bA = cw2[tk][p];
                const float wB = cw1[tk][p + 1], bB = cw2[tk][p + 1];
                qa.x += wA * rA.x + wB * rB.x; qa.y += wA * rA.y + wB * rB.y;
                qa.z += wA * rA.z + wB * rB.z; qa.w += wA * rA.w + wB * rB.w;
                ka.x += bA * rA.x + bB * rB.x; ka.y += bA * rA.y + bB * rB.y;
                ka.z += bA * rA.z + bB * rB.z; ka.w += bA * rA.w + bB * rB.w;
            }
            if (p < n) {
                const float4 rA = *(const float4*)(neurons + (size_t)ci[tk][p] * D_ + tt * 4);
                const float wA = cw1[tk][p], bA = cw2[tk][p];
                qa.x += wA * rA.x; qa.y += wA * rA.y; qa.z += wA * rA.z; qa.w += wA * rA.w;
                ka.x += bA * rA.x; ka.y += bA * rA.y; ka.z += bA * rA.z; ka.w += bA * rA.w;
            }
            *(float4*)(Q + (size_t)token * D_ + tt * 4) = qa;
            *(float4*)(K + (size_t)token * D_ + tt * 4) = ka;
        }
    } else {
        const float tv = tauV[token];
        float sV = 0.f, mV = 0.f;
        for (int p = tt; p < n; p += 128) {
            float s = act[tk][ci[tk][p]];
            float rv = s - tv;
            float gv = (rv > 0.f) ? rv : 1e-8f * __expf(rv);
            float egv = __expf(gv) - 1.f;
            cw1[tk][p] = egv;
            sV += egv; mV = fmaxf(mV, egv);
        }
        sV = wave_sum(sV); mV = wave_max(mV);
        if (lane == 0) { red[tk][sw][0] = sV; red[tk][sw][1] = mV; }
        __syncthreads();
        const float scV = tanhf(fmaxf(red[tk][0][1], red[tk][1][1]))
                        / (red[tk][0][0] + red[tk][1][0] + 1e-8f);
        __syncthreads();

        const float vp0 = pose[token * 2], vp1 = pose[token * 2 + 1];
        float plv = 0.f;
        for (int p = tt; p < n; p += 128) {
            int e = ci[tk][p];
            int id = idx[e];
            float m = msk[e], a = act[tk][e];
            float gv = cw1[tk][p] * scV;
            cw1[tk][p] = a * gv * m;
            ci[tk][p] = id;
            float d0 = vp0 - npos[id * 2], d1 = vp1 - npos[id * 2 + 1];
            plv += gv * (d0 * d0 + d1 * d1) * m;
        }
        plv = wave_sum(plv);
        if (lane == 0) red[tk][sw][0] = plv;
        __syncthreads();
        if (tt == 0 && tk < count) {
            int chunk = (token & 1023) >> 7;
            atomicAdd(&posacc[16 + chunk], red[tk][0][0] + red[tk][1][0]);
            atomicAdd(&posacc[24 + chunk], cm);
        }

        if (tk < count) {
            float4 va = {0,0,0,0};
            int p = 0;
            for (; p + 1 < n; p += 2) {
                const float4 rA = *(const float4*)(neurons + (size_t)ci[tk][p] * D_ + tt * 4);
                const float4 rB = *(const float4*)(neurons + (size_t)ci[tk][p + 1] * D_ + tt * 4);
                const float wA = cw1[tk][p], wB = cw1[tk][p + 1];
                va.x += wA * rA.x + wB * rB.x; va.y += wA * rA.y + wB * rB.y;
                va.z += wA * rA.z + wB * rB.z; va.w += wA * rA.w + wB * rB.w;
            }
            if (p < n) {
                const float4 rA = *(const float4*)(neurons + (size_t)ci[tk][p] * D_ + tt * 4);
                const float wA = cw1[tk][p];
                va.x += wA * rA.x; va.y += wA * rA.y; va.z += wA * rA.z; va.w += wA * rA.w;
            }
            *(float4*)(V + (size_t)token * D_ + tt * 4) = va;
        }
    }
}

// ---------- attention partials (unchanged) ----------
__global__ __launch_bounds__(128) void attn_partial_kernel(
    const float* __restrict__ Q, const float* __restrict__ K,
    const float* __restrict__ V,
    float* __restrict__ pm, float* __restrict__ pl, float* __restrict__ po)
{
    const int xx = blockIdx.x & 7;
    int k = blockIdx.x >> 3;             // 0..143
    const int bh = xx + 8 * (k >= 72);
    k = (k >= 72) ? k - 72 : k;          // 0..71
    int rblk = 0;
    while (k >= 2 * (rblk + 1)) { k -= 2 * (rblk + 1); rblk++; }
    const int sp = k;
    const int b = bh >> 3, h = bh & 7;
    const int j0 = sp * 64;
    const int rbase = rblk * 128;

    const int t = threadIdx.x;
    const int p = t >> 1, dhalf = t & 1;
    const int r0 = rbase + p, r1 = r0 + 64;

    __shared__ float Kl[64 * 64];
    __shared__ float Vl[64 * 64];

    {
        const float* Kbase = K + (size_t)b * S_ * D_ + h * DH_;
        const float* Vbase = V + (size_t)b * S_ * D_ + h * DH_;
        const int lrow = t >> 4, lcol = (t & 15) * 4;
        #pragma unroll
        for (int kk = 0; kk < 8; kk++) {
            const int row = lrow + kk * 8;
            const size_t goff = (size_t)(j0 + row) * D_ + lcol;
            *(float4*)(&Kl[row * 64 + lcol]) = *(const float4*)(Kbase + goff);
            *(float4*)(&Vl[row * 64 + lcol]) = *(const float4*)(Vbase + goff);
        }
    }

    float q0[32], q1[32];
    {
        const float* Qb = Q + (size_t)b * S_ * D_ + h * DH_ + dhalf * 32;
        const float4* qa = (const float4*)(Qb + (size_t)r0 * D_);
        const float4* qb = (const float4*)(Qb + (size_t)r1 * D_);
        #pragma unroll
        for (int kk = 0; kk < 8; kk++) {
            float4 v = qa[kk];
            q0[4*kk] = v.x; q0[4*kk+1] = v.y; q0[4*kk+2] = v.z; q0[4*kk+3] = v.w;
            float4 u = qb[kk];
            q1[4*kk] = u.x; q1[4*kk+1] = u.y; q1[4*kk+2] = u.z; q1[4*kk+3] = u.w;
        }
    }
    float o0[32], o1[32];
    #pragma unroll
    for (int d = 0; d < 32; d++) { o0[d] = 0.f; o1[d] = 0.f; }
    float m0 = -INFINITY, m1 = -INFINITY, l0 = 0.f, l1 = 0.f;

    __syncthreads();

    for (int bb = 0; bb < 8; bb++) {
        const int jb = bb * 8;
        float s0[8], s1[8];
        #pragma unroll
        for (int jj = 0; jj < 8; jj++) {
            const float* kr = &Kl[(jb + jj) * 64 + dhalf * 32];
            float pa0 = 0.f, pb0 = 0.f, pa1 = 0.f, pb1 = 0.f;
            #pragma unroll
            for (int d = 0; d < 32; d += 8) {
                float4 ka = *(const float4*)(kr + d);
                float4 kb = *(const float4*)(kr + d + 4);
                pa0 += q0[d]*ka.x + q0[d+1]*ka.y + q0[d+2]*ka.z + q0[d+3]*ka.w;
                pb0 += q0[d+4]*kb.x + q0[d+5]*kb.y + q0[d+6]*kb.z + q0[d+7]*kb.w;
                pa1 += q1[d]*ka.x + q1[d+1]*ka.y + q1[d+2]*ka.z + q1[d+3]*ka.w;
                pb1 += q1[d+4]*kb.x + q1[d+5]*kb.y + q1[d+6]*kb.z + q1[d+7]*kb.w;
            }
            float f0 = pa0 + pb0, f1 = pa1 + pb1;
            f0 += __shfl_xor(f0, 1);
            f1 += __shfl_xor(f1, 1);
            const int jg = j0 + jb + jj;
            s0[jj] = (jg <= r0) ? f0 * 0.125f : -INFINITY;
            s1[jj] = (jg <= r1) ? f1 * 0.125f : -INFINITY;
        }
        float t0 = s0[0], t1 = s1[0];
        #pragma unroll
        for (int jj = 1; jj < 8; jj++) { t0 = fmaxf(t0, s0[jj]); t1 = fmaxf(t1, s1[jj]); }
        const float nm0 = fmaxf(m0, t0), nm1 = fmaxf(m1, t1);
        const float base0 = (nm0 == -INFINITY) ? 0.f : nm0;
        const float base1 = (nm1 == -INFINITY) ? 0.f : nm1;
        const float al0 = __expf(m0 - base0);
        const float al1 = __expf(m1 - base1);
        float ps0 = 0.f, ps1 = 0.f;
        #pragma unroll
        for (int jj = 0; jj < 8; jj++) {
            s0[jj] = __expf(s0[jj] - base0); ps0 += s0[jj];
            s1[jj] = __expf(s1[jj] - base1); ps1 += s1[jj];
        }
        l0 = l0 * al0 + ps0; l1 = l1 * al1 + ps1;
        #pragma unroll
        for (int d = 0; d < 32; d++) { o0[d] *= al0; o1[d] *= al1; }
        #pragma unroll
        for (int jj = 0; jj < 8; jj++) {
            const float* vr = &Vl[(jb + jj) * 64 + dhalf * 32];
            const float w0 = s0[jj], w1 = s1[jj];
            #pragma unroll
            for (int d = 0; d < 32; d += 4) {
                float4 vv = *(const float4*)(vr + d);
                o0[d]   += w0 * vv.x; o0[d+1] += w0 * vv.y;
                o0[d+2] += w0 * vv.z; o0[d+3] += w0 * vv.w;
                o1[d]   += w1 * vv.x; o1[d+1] += w1 * vv.y;
                o1[d+2] += w1 * vv.z; o1[d+3] += w1 * vv.w;
            }
        }
        m0 = nm0; m1 = nm1;
    }

    if (j0 <= r0) {
        const int g = r0 >> 6;
        const size_t slot = (size_t)bh * NSLOT_BH + 32 * g * (g + 1)
                          + (size_t)(r0 & 63) * (g + 1) + sp;
        if (dhalf == 0) { pm[slot] = m0; pl[slot] = l0; }
        float* od = po + slot * 64 + dhalf * 32;
        #pragma unroll
        for (int kk = 0; kk < 8; kk++) {
            float4 v; v.x = o0[4*kk]; v.y = o0[4*kk+1]; v.z = o0[4*kk+2]; v.w = o0[4*kk+3];
            *(float4*)(od + 4*kk) = v;
        }
    }
    {
        const int g = r1 >> 6;
        const size_t slot = (size_t)bh * NSLOT_BH + 32 * g * (g + 1)
                          + (size_t)(r1 & 63) * (g + 1) + sp;
        if (dhalf == 0) { pm[slot] = m1; pl[slot] = l1; }
        float* od = po + slot * 64 + dhalf * 32;
        #pragma unroll
        for (int kk = 0; kk < 8; kk++) {
            float4 v; v.x = o1[4*kk]; v.y = o1[4*kk+1]; v.z = o1[4*kk+2]; v.w = o1[4*kk+3];
            *(float4*)(od + 4*kk) = v;
        }
    }
}

// ---------- merge split partials (single-pass online merge) ----------
__global__ __launch_bounds__(256) void attn_combine_kernel(
    const float* __restrict__ pm, const float* __restrict__ pl,
    const float* __restrict__ po, float* __restrict__ AO)
{
    const int gth = blockIdx.x * 256 + threadIdx.x;
    const int r = gth >> 6, d = gth & 63;
    const int i = r & 1023, bh = r >> 10;
    const int b = bh >> 3, h = bh & 7;
    const int g = i >> 6;
    const int ns = g + 1;
    const size_t slot0 = (size_t)bh * NSLOT_BH + 32 * g * (g + 1)
                       + (size_t)(i & 63) * (g + 1);
    float mstar = -INFINITY, lstar = 0.f, ostar = 0.f;
    for (int s = 0; s < ns; s++) {
        const float mi = pm[slot0 + s];
        const float nm = fmaxf(mstar, mi);
        const float a = __expf(mstar - nm);
        const float w = __expf(mi - nm);
        lstar = lstar * a + pl[slot0 + s] * w;
        ostar = ostar * a + po[(slot0 + s) * 64 + d] * w;
        mstar = nm;
    }
    AO[((size_t)(b * S_ + i)) * D_ + h * DH_ + d] = ostar / lstar;
}

// ---------- projection: 4 tokens per block (R13 version) ----------
__global__ __launch_bounds__(256) void proj_kernel(
    const float* __restrict__ A, const float* __restrict__ W,
    float* __restrict__ out)
{
    __shared__ float rows[4][D_];
    const int blk = blockIdx.x;
    const int t = threadIdx.x;
    {
        const float4* af = (const float4*)(A + (size_t)blk * 4 * D_);
        float4* rf = (float4*)&rows[0][0];
        rf[t] = af[t]; rf[t + 256] = af[t + 256];
    }
    __syncthreads();
    float acc0[4] = {0,0,0,0}, acc1[4] = {0,0,0,0};
    for (int d = 0; d < D_; d += 4) {
        float r0[4], r1[4], r2[4], r3[4];
        *(float4*)r0 = *(const float4*)&rows[0][d];
        *(float4*)r1 = *(const float4*)&rows[1][d];
        *(float4*)r2 = *(const float4*)&rows[2][d];
        *(float4*)r3 = *(const float4*)&rows[3][d];
        #pragma unroll
        for (int j = 0; j < 4; j++) {
            float w0 = W[(size_t)(d + j) * D_ + t];
            float w1 = W[(size_t)(d + j) * D_ + t + 256];
            acc0[0] += r0[j] * w0; acc1[0] += r0[j] * w1;
            acc0[1] += r1[j] * w0; acc1[1] += r1[j] * w1;
            acc0[2] += r2[j] * w0; acc1[2] += r2[j] * w1;
            acc0[3] += r3[j] * w0; acc1[3] += r3[j] * w1;
        }
    }
    #pragma unroll
    for (int k = 0; k < 4; k++) {
        const size_t base = (size_t)(blk * 4 + k) * D_;
        out[base + t] = acc0[k];
        out[base + t + 256] = acc1[k];
    }
}

// ---------- pos-loss helpers ----------
__global__ void zero_acc_kernel(float* acc) {
    if (threadIdx.x < 32) acc[threadIdx.x] = 0.f;
}
__global__ void ploss_kernel(const float* __restrict__ acc, float* __restrict__ out) {
    float ssum = 0.f;
    for (int c = 0; c < 8; c++) {
        ssum += acc[c]      / (acc[8 + c]  + 1e-8f);
        ssum += acc[16 + c] / (acc[24 + c] + 1e-8f);
    }
    out[0] = ssum * 0.125f;
}

extern "C" void kernel_launch(void* const* d_in, const int* in_sizes, int n_in,
                              void* d_out, int out_size, void* d_ws, size_t ws_size,
                              hipStream_t stream) {
    const float* x          = (const float*)d_in[0];
    const float* qk_pos     = (const float*)d_in[1];
    const float* v_pos      = (const float*)d_in[2];
    const float* tauQ       = (const float*)d_in[3];
    const float* tauK       = (const float*)d_in[4];
    const float* tauV       = (const float*)d_in[5];
    const float* qk_neurons = (const float*)d_in[6];
    const float* v_neurons  = (const float*)d_in[7];
    const float* npos_qk    = (const float*)d_in[8];
    const float* npos_v     = (const float*)d_in[9];
    const int*   cm_qk      = (const int*)d_in[10];
    const int*   cm_v       = (const int*)d_in[11];
    const float* pos_min    = (const float*)d_in[12];
    const float* pos_range  = (const float*)d_in[13];
    const float* expand_O   = (const float*)d_in[14];

    float* ws = (float*)d_ws;
    const size_t TDf = (size_t)NTOK * D_;     // 1,048,576 floats
    float* Q   = ws;
    float* K   = ws + TDf;
    float* V   = ws + 2 * TDf;
    float* AO  = ws + 3 * TDf;
    float* acc = ws + 4 * TDf;                // 64 float slots
    int*   order_qk = (int*)(ws + 4 * TDf + 64);
    int*   order_v  = order_qk + NTOK;
    int2*  desc_qk  = (int2*)(order_v + NTOK);
    int2*  desc_v   = desc_qk + NG2;
    const size_t head = 4 * TDf + 64 + 2 * NTOK + 4 * NG2;  // float units

    float* pm = ws + head;                    // NSLOTS
    float* pl = pm + (size_t)NSLOTS;
    float* po = pl + (size_t)NSLOTS;          // NSLOTS*64

    float* out = (float*)d_out;

    zero_acc_kernel<<<1, 64, 0, stream>>>(acc);
    sort_tokens_kernel<<<2, 1024, 0, stream>>>(qk_pos, v_pos, pos_min, pos_range,
                                               order_qk, order_v, desc_qk, desc_v);
    qkv_fused<<<2 * NG2, 256, 0, stream>>>(desc_qk, order_qk, desc_v, order_v,
                                           x, qk_pos, v_pos, tauQ, tauK, tauV,
                                           qk_neurons, v_neurons, npos_qk, npos_v,
                                           cm_qk, cm_v, pos_min, pos_range,
                                           Q, K, V, acc);
    attn_partial_kernel<<<1152, 128, 0, stream>>>(Q, K, V, pm, pl, po);
    attn_combine_kernel<<<(NROWS * 64) / 256, 256, 0, stream>>>(pm, pl, po, AO);
    proj_kernel<<<NTOK / 4, 256, 0, stream>>>(AO, expand_O, out);
    ploss_kernel<<<1, 1, 0, stream>>>(acc, out + TDf);
}